// Round 2
// baseline (323.311 us; speedup 1.0000x reference)
//
#include <hip/hip_runtime.h>
#include <hip/hip_bf16.h>
#include <cstdint>
#include <cstddef>

#define BN 8192
#define DN 256

typedef short bf16x8 __attribute__((ext_vector_type(8)));
typedef float f32x4 __attribute__((ext_vector_type(4)));

// ---- workspace layout ----
// shorts (bf16) weight packs, all B^T layout [n][k] unless noted:
#define O_WINT   0         // [256][256]
#define O_GKT    65536     // [768][256]
#define O_GRKT   262144    // [768][256]
#define O_WQT    458752    // [256][256]
#define O_WK     524288    // native [d][h*64+dk] (already B^T per head)
#define O_WVT    589824    // [(h,dk)=256][256]
#define O_WOT    655360    // [256][256]
#define O_WCTXT  720896    // [256][256]
#define O_WGT    786432    // [256][512]
#define O_WMT    917504    // [256][256]
#define W_TOTAL  983040
#define OB_GRUF  ((size_t)(2*1024*1024))            // gru_out fp32 [B][256]  (8.4 MB)
#define OB_QK    ((size_t)(OB_GRUF + 8388608))      // qk / wmem bf16 [B][4][256] (16.8 MB)

__device__ __forceinline__ short f2bf(float x){
  unsigned u = __builtin_bit_cast(unsigned, x);
  u = (u + 0x7fffu + ((u >> 16) & 1u)) >> 16;
  return (short)u;
}
__device__ __forceinline__ float bf2f(short s){
  unsigned u = ((unsigned)(unsigned short)s) << 16;
  return __builtin_bit_cast(float, u);
}
__device__ __forceinline__ float sigm(float x){ return 1.f/(1.f+__expf(-x)); }
__device__ __forceinline__ float tanh_(float x){
  x = fminf(20.f, fmaxf(-20.f, x));
  float e = __expf(-2.f*x);
  return (1.f - e)/(1.f + e);
}
__device__ __forceinline__ f32x4 mfma16(bf16x8 a, bf16x8 b, f32x4 c){
  return __builtin_amdgcn_mfma_f32_16x16x32_bf16(a, b, c, 0, 0, 0);
}
// load 8 consecutive fp32 (caller pre-offsets for lane) and cvt -> bf16 frag
__device__ __forceinline__ bf16x8 frag_f32(const float* p){
  float4 a = *reinterpret_cast<const float4*>(p);
  float4 b = *reinterpret_cast<const float4*>(p+4);
  bf16x8 v;
  v[0]=f2bf(a.x); v[1]=f2bf(a.y); v[2]=f2bf(a.z); v[3]=f2bf(a.w);
  v[4]=f2bf(b.x); v[5]=f2bf(b.y); v[6]=f2bf(b.z); v[7]=f2bf(b.w);
  return v;
}

// ============================ K0: weight pack ============================
__global__ __launch_bounds__(256) void k_prep(
    const float* __restrict__ W_in, const float* __restrict__ gru_k,
    const float* __restrict__ gru_rk, const float* __restrict__ Wq,
    const float* __restrict__ Wk, const float* __restrict__ Wv,
    const float* __restrict__ Wo, const float* __restrict__ W_ctx,
    const float* __restrict__ W_gate, const float* __restrict__ W_mem,
    short* __restrict__ wp)
{
  int idx = blockIdx.x*256 + threadIdx.x;
  if (idx < 65536){ int n=idx>>8, k=idx&255; wp[O_WINT+idx]=f2bf(W_in[k*256+n]); return; }
  idx -= 65536;
  if (idx < 196608){ int n=idx>>8, k=idx&255; wp[O_GKT+idx]=f2bf(gru_k[k*768+n]); return; }
  idx -= 196608;
  if (idx < 196608){ int n=idx>>8, k=idx&255; wp[O_GRKT+idx]=f2bf(gru_rk[k*768+n]); return; }
  idx -= 196608;
  if (idx < 65536){ int n=idx>>8, k=idx&255; wp[O_WQT+idx]=f2bf(Wq[k*256+n]); return; }
  idx -= 65536;
  if (idx < 65536){ wp[O_WK+idx]=f2bf(Wk[idx]); return; }
  idx -= 65536;
  if (idx < 65536){ int n=idx>>8, k=idx&255; wp[O_WVT+idx]=f2bf(Wv[k*256+n]); return; }
  idx -= 65536;
  if (idx < 65536){ int n=idx>>8, k=idx&255; wp[O_WOT+idx]=f2bf(Wo[k*256+n]); return; }
  idx -= 65536;
  if (idx < 65536){ int n=idx>>8, k=idx&255; wp[O_WCTXT+idx]=f2bf(W_ctx[k*256+n]); return; }
  idx -= 65536;
  if (idx < 131072){ int n=idx>>9, k=idx&511; wp[O_WGT+idx]=f2bf(W_gate[k*256+n]); return; }
  idx -= 131072;
  if (idx < 65536){ int n=idx>>8, k=idx&255; wp[O_WMT+idx]=f2bf(W_mem[k*256+n]); }
}

// ============ K1: z_t -> new_entry -> GRU -> q -> qk (32 rows/block) ============
__global__ __launch_bounds__(256) void k_gru(
    const float* __restrict__ inputs, const float* __restrict__ h_prev,
    const float* __restrict__ b_in, const float* __restrict__ gru_b,
    const float* __restrict__ bq, const float* __restrict__ b_mem,
    const short* __restrict__ wp,
    float* __restrict__ gruout_f, short* __restrict__ qk_bf,
    float* __restrict__ d_out)
{
  const int tid = threadIdx.x;
  const int wv = tid >> 6, lane = tid & 63;
  const int r16 = lane & 15, kk = (lane >> 4) * 8, vr4 = (lane >> 4) * 4;
  const int row0 = blockIdx.x * 32;
  const int cb = wv * 64;

  __shared__ __attribute__((aligned(16))) short sZ[32*272];
  __shared__ __attribute__((aligned(16))) short sG[32*272];

  // ---- Phase A: z_t = inputs @ W_in + b_in -> sZ (bf16)
  {
    f32x4 acc[2][4] = {};
    for (int k0=0; k0<256; k0+=32){
      bf16x8 a[2], b[4];
      #pragma unroll
      for (int rt=0; rt<2; rt++)
        a[rt] = frag_f32(inputs + (size_t)(row0+rt*16+r16)*256 + k0 + kk);
      #pragma unroll
      for (int ct=0; ct<4; ct++)
        b[ct] = *reinterpret_cast<const bf16x8*>(wp + O_WINT + (cb+ct*16+r16)*256 + k0 + kk);
      #pragma unroll
      for (int rt=0; rt<2; rt++)
        #pragma unroll
        for (int ct=0; ct<4; ct++)
          acc[rt][ct] = mfma16(a[rt], b[ct], acc[rt][ct]);
    }
    #pragma unroll
    for (int rt=0; rt<2; rt++)
      #pragma unroll
      for (int ct=0; ct<4; ct++)
        #pragma unroll
        for (int v=0; v<4; v++){
          int lrow = rt*16 + vr4 + v, col = cb + ct*16 + r16;
          sZ[lrow*272 + col] = f2bf(acc[rt][ct][v] + b_in[col]);
        }
  }
  __syncthreads();

  // ---- Phase B: new_entry = z_t @ W_mem + b_mem -> d_out memory slot 9 (fp32)
  {
    f32x4 acc[2][4] = {};
    for (int k0=0; k0<256; k0+=32){
      bf16x8 a[2], b[4];
      #pragma unroll
      for (int rt=0; rt<2; rt++)
        a[rt] = *reinterpret_cast<const bf16x8*>(sZ + (rt*16+r16)*272 + k0 + kk);
      #pragma unroll
      for (int ct=0; ct<4; ct++)
        b[ct] = *reinterpret_cast<const bf16x8*>(wp + O_WMT + (cb+ct*16+r16)*256 + k0 + kk);
      #pragma unroll
      for (int rt=0; rt<2; rt++)
        #pragma unroll
        for (int ct=0; ct<4; ct++)
          acc[rt][ct] = mfma16(a[rt], b[ct], acc[rt][ct]);
    }
    float* om = d_out + (size_t)BN*256;
    #pragma unroll
    for (int rt=0; rt<2; rt++)
      #pragma unroll
      for (int ct=0; ct<4; ct++)
        #pragma unroll
        for (int v=0; v<4; v++){
          int grow = row0 + rt*16 + vr4 + v, col = cb + ct*16 + r16;
          om[(size_t)grow*2560 + 2304 + col] = acc[rt][ct][v] + b_mem[col];
        }
  }

  // ---- Phase C: GRU (reset_after) -> gru_out (sG bf16 + global fp32)
  for (int ct=0; ct<4; ct++){
    const int c = cb + ct*16;
    f32x4 az[2] = {}, arr[2] = {}, ax[2] = {}, ah[2] = {};
    for (int k0=0; k0<256; k0+=32){
      bf16x8 aZ[2], aH[2];
      #pragma unroll
      for (int rt=0; rt<2; rt++){
        aZ[rt] = *reinterpret_cast<const bf16x8*>(sZ + (rt*16+r16)*272 + k0 + kk);
        aH[rt] = frag_f32(h_prev + (size_t)(row0+rt*16+r16)*256 + k0 + kk);
      }
      bf16x8 bz1 = *reinterpret_cast<const bf16x8*>(wp + O_GKT  + (c      +r16)*256 + k0 + kk);
      bf16x8 br1 = *reinterpret_cast<const bf16x8*>(wp + O_GKT  + (256+c  +r16)*256 + k0 + kk);
      bf16x8 bx1 = *reinterpret_cast<const bf16x8*>(wp + O_GKT  + (512+c  +r16)*256 + k0 + kk);
      bf16x8 bz2 = *reinterpret_cast<const bf16x8*>(wp + O_GRKT + (c      +r16)*256 + k0 + kk);
      bf16x8 br2 = *reinterpret_cast<const bf16x8*>(wp + O_GRKT + (256+c  +r16)*256 + k0 + kk);
      bf16x8 bh2 = *reinterpret_cast<const bf16x8*>(wp + O_GRKT + (512+c  +r16)*256 + k0 + kk);
      #pragma unroll
      for (int rt=0; rt<2; rt++){
        az[rt]  = mfma16(aZ[rt], bz1, az[rt]);  az[rt]  = mfma16(aH[rt], bz2, az[rt]);
        arr[rt] = mfma16(aZ[rt], br1, arr[rt]); arr[rt] = mfma16(aH[rt], br2, arr[rt]);
        ax[rt]  = mfma16(aZ[rt], bx1, ax[rt]);
        ah[rt]  = mfma16(aH[rt], bh2, ah[rt]);
      }
    }
    #pragma unroll
    for (int rt=0; rt<2; rt++)
      #pragma unroll
      for (int v=0; v<4; v++){
        int lrow = rt*16 + vr4 + v, grow = row0 + lrow, col = c + r16;
        float z  = sigm(az[rt][v]  + gru_b[col]     + gru_b[768+col]);
        float r  = sigm(arr[rt][v] + gru_b[256+col] + gru_b[768+256+col]);
        float hc = tanh_(ax[rt][v] + gru_b[512+col] + r*(ah[rt][v] + gru_b[768+512+col]));
        float hp = h_prev[(size_t)grow*256 + col];
        float go = z*hp + (1.f - z)*hc;
        sG[lrow*272 + col] = f2bf(go);
        gruout_f[(size_t)grow*256 + col] = go;
      }
  }
  __syncthreads();

  // ---- Phase D: q = gru_out @ Wq + bq -> sZ (reuse)
  {
    f32x4 acc[2][4] = {};
    for (int k0=0; k0<256; k0+=32){
      bf16x8 a[2], b[4];
      #pragma unroll
      for (int rt=0; rt<2; rt++)
        a[rt] = *reinterpret_cast<const bf16x8*>(sG + (rt*16+r16)*272 + k0 + kk);
      #pragma unroll
      for (int ct=0; ct<4; ct++)
        b[ct] = *reinterpret_cast<const bf16x8*>(wp + O_WQT + (cb+ct*16+r16)*256 + k0 + kk);
      #pragma unroll
      for (int rt=0; rt<2; rt++)
        #pragma unroll
        for (int ct=0; ct<4; ct++)
          acc[rt][ct] = mfma16(a[rt], b[ct], acc[rt][ct]);
    }
    __syncthreads();   // everyone done reading sZ (z_t dead) before overwrite
    #pragma unroll
    for (int rt=0; rt<2; rt++)
      #pragma unroll
      for (int ct=0; ct<4; ct++)
        #pragma unroll
        for (int v=0; v<4; v++){
          int lrow = rt*16 + vr4 + v, col = cb + ct*16 + r16;
          sZ[lrow*272 + col] = f2bf(acc[rt][ct][v] + bq[col]);
        }
  }
  __syncthreads();

  // ---- Phase E: qk_h = q_h @ Wk_h^T  (head = wv) -> global bf16 [B][4][256]
  for (int nb=0; nb<4; nb++){
    f32x4 acc[2][4] = {};
    for (int k0=0; k0<64; k0+=32){
      bf16x8 a[2], b[4];
      #pragma unroll
      for (int rt=0; rt<2; rt++)
        a[rt] = *reinterpret_cast<const bf16x8*>(sZ + (rt*16+r16)*272 + wv*64 + k0 + kk);
      #pragma unroll
      for (int ct=0; ct<4; ct++)
        b[ct] = *reinterpret_cast<const bf16x8*>(wp + O_WK + (nb*64+ct*16+r16)*256 + wv*64 + k0 + kk);
      #pragma unroll
      for (int rt=0; rt<2; rt++)
        #pragma unroll
        for (int ct=0; ct<4; ct++)
          acc[rt][ct] = mfma16(a[rt], b[ct], acc[rt][ct]);
    }
    #pragma unroll
    for (int rt=0; rt<2; rt++)
      #pragma unroll
      for (int ct=0; ct<4; ct++)
        #pragma unroll
        for (int v=0; v<4; v++){
          int grow = row0 + rt*16 + vr4 + v, d = nb*64 + ct*16 + r16;
          qk_bf[(size_t)grow*1024 + wv*256 + d] = f2bf(acc[rt][ct][v]);
        }
  }
}

// ===== K2: scores/softmax/wmem + memory shift-copy; 1 wave per row =====
__global__ __launch_bounds__(256) void k_attn(
    const float* __restrict__ mem, short* __restrict__ qkwm,
    float* __restrict__ d_out)
{
  const int wv = threadIdx.x >> 6, lane = threadIdx.x & 63;
  const int b = blockIdx.x*4 + wv;
  const float* mrow = mem + (size_t)b*2560;
  float* orow = d_out + (size_t)BN*256 + (size_t)b*2560;

  float qv[4][4];
  #pragma unroll
  for (int h=0; h<4; h++){
    short4 s = *reinterpret_cast<const short4*>(qkwm + (size_t)b*1024 + h*256 + lane*4);
    qv[h][0]=bf2f(s.x); qv[h][1]=bf2f(s.y); qv[h][2]=bf2f(s.z); qv[h][3]=bf2f(s.w);
  }
  float4 mv[10];
  float sc[10][4];
  #pragma unroll
  for (int m=0; m<10; m++){
    mv[m] = *reinterpret_cast<const float4*>(mrow + m*256 + lane*4);
    if (m >= 1) *reinterpret_cast<float4*>(orow + (m-1)*256 + lane*4) = mv[m];  // memory shift
    #pragma unroll
    for (int h=0; h<4; h++){
      float p = qv[h][0]*mv[m].x + qv[h][1]*mv[m].y + qv[h][2]*mv[m].z + qv[h][3]*mv[m].w;
      p += __shfl_xor(p,32); p += __shfl_xor(p,16); p += __shfl_xor(p,8);
      p += __shfl_xor(p,4);  p += __shfl_xor(p,2);  p += __shfl_xor(p,1);
      sc[m][h] = p * 0.125f;   // / sqrt(64)
    }
  }
  #pragma unroll
  for (int h=0; h<4; h++){
    float mx = sc[0][h];
    #pragma unroll
    for (int m=1; m<10; m++) mx = fmaxf(mx, sc[m][h]);
    float s = 0.f;
    #pragma unroll
    for (int m=0; m<10; m++){ float e = __expf(sc[m][h]-mx); sc[m][h]=e; s+=e; }
    float inv = 1.f/s;
    #pragma unroll
    for (int m=0; m<10; m++) sc[m][h] *= inv;
  }
  float w4[4][4] = {};
  #pragma unroll
  for (int m=0; m<10; m++)
    #pragma unroll
    for (int h=0; h<4; h++){
      w4[h][0] += sc[m][h]*mv[m].x; w4[h][1] += sc[m][h]*mv[m].y;
      w4[h][2] += sc[m][h]*mv[m].z; w4[h][3] += sc[m][h]*mv[m].w;
    }
  #pragma unroll
  for (int h=0; h<4; h++){
    short4 o; o.x=f2bf(w4[h][0]); o.y=f2bf(w4[h][1]); o.z=f2bf(w4[h][2]); o.w=f2bf(w4[h][3]);
    *reinterpret_cast<short4*>(qkwm + (size_t)b*1024 + h*256 + lane*4) = o;  // wmem over dead qk
  }
}

// ==== K3: ctx -> Wo -> LN -> W_ctx -> gate -> LN -> h_corr (32 rows/block) ====
__device__ __forceinline__ void ln_stats(const float* sF, float sPart[32][8][2],
                                         float sMV[32][2], int tid){
  int r = tid>>3, q = tid&7;
  float s1=0.f, s2=0.f;
  const float* p = sF + r*264 + q*32;
  #pragma unroll
  for (int i=0; i<32; i++){ float v=p[i]; s1+=v; s2+=v*v; }
  sPart[r][q][0]=s1; sPart[r][q][1]=s2;
  __syncthreads();
  if (tid < 32){
    float a=0.f, b2=0.f;
    #pragma unroll
    for (int j=0; j<8; j++){ a+=sPart[tid][j][0]; b2+=sPart[tid][j][1]; }
    float mu = a*(1.f/256.f);
    float var = fmaxf(b2*(1.f/256.f) - mu*mu, 0.f);
    sMV[tid][0]=mu; sMV[tid][1]=rsqrtf(var + 1e-3f);
  }
  __syncthreads();
}

__global__ __launch_bounds__(256) void k_out(
    const short* __restrict__ wmem, const short* __restrict__ wp,
    const float* __restrict__ bv, const float* __restrict__ bo,
    const float* __restrict__ g_attn, const float* __restrict__ beta_attn,
    const float* __restrict__ b_ctx, const float* __restrict__ b_gate,
    const float* __restrict__ g_out, const float* __restrict__ beta_out,
    const float* __restrict__ gruout_f, float* __restrict__ d_out)
{
  const int tid = threadIdx.x, wv = tid>>6, lane = tid&63;
  const int r16 = lane&15, kk = (lane>>4)*8, vr4 = (lane>>4)*4;
  const int row0 = blockIdx.x*32, cb = wv*64;
  __shared__ __attribute__((aligned(16))) short sC[32*272];
  __shared__ __attribute__((aligned(16))) float sF[32*264];
  __shared__ __attribute__((aligned(16))) float sPart[32][8][2];
  __shared__ __attribute__((aligned(16))) float sMV[32][2];

  // Phase A: ctx_h = wmem_h @ Wv_h + bv  (head = wv) -> sC
  {
    f32x4 acc[2][4] = {};
    for (int k0=0; k0<256; k0+=32){
      bf16x8 a[2], b[4];
      #pragma unroll
      for (int rt=0; rt<2; rt++)
        a[rt] = *reinterpret_cast<const bf16x8*>(wmem + (size_t)(row0+rt*16+r16)*1024 + wv*256 + k0 + kk);
      #pragma unroll
      for (int ct=0; ct<4; ct++)
        b[ct] = *reinterpret_cast<const bf16x8*>(wp + O_WVT + (wv*64+ct*16+r16)*256 + k0 + kk);
      #pragma unroll
      for (int rt=0; rt<2; rt++)
        #pragma unroll
        for (int ct=0; ct<4; ct++)
          acc[rt][ct] = mfma16(a[rt], b[ct], acc[rt][ct]);
    }
    #pragma unroll
    for (int rt=0; rt<2; rt++)
      #pragma unroll
      for (int ct=0; ct<4; ct++)
        #pragma unroll
        for (int v=0; v<4; v++){
          int lrow = rt*16 + vr4 + v, col = wv*64 + ct*16 + r16;
          sC[lrow*272 + col] = f2bf(acc[rt][ct][v] + bv[col]);
        }
  }
  __syncthreads();

  // Phase B: context = ctx_all @ Wo + bo -> sF (fp32)
  {
    f32x4 acc[2][4] = {};
    for (int k0=0; k0<256; k0+=32){
      bf16x8 a[2], b[4];
      #pragma unroll
      for (int rt=0; rt<2; rt++)
        a[rt] = *reinterpret_cast<const bf16x8*>(sC + (rt*16+r16)*272 + k0 + kk);
      #pragma unroll
      for (int ct=0; ct<4; ct++)
        b[ct] = *reinterpret_cast<const bf16x8*>(wp + O_WOT + (cb+ct*16+r16)*256 + k0 + kk);
      #pragma unroll
      for (int rt=0; rt<2; rt++)
        #pragma unroll
        for (int ct=0; ct<4; ct++)
          acc[rt][ct] = mfma16(a[rt], b[ct], acc[rt][ct]);
    }
    #pragma unroll
    for (int rt=0; rt<2; rt++)
      #pragma unroll
      for (int ct=0; ct<4; ct++)
        #pragma unroll
        for (int v=0; v<4; v++){
          int lrow = rt*16 + vr4 + v, col = cb + ct*16 + r16;
          sF[lrow*264 + col] = acc[rt][ct][v] + bo[col];
        }
  }
  __syncthreads();

  // LN1 (g_attn/beta_attn): sF -> sC (bf16)
  ln_stats(sF, sPart, sMV, tid);
  {
    int r = tid>>3, q = tid&7;
    float mu = sMV[r][0], rs = sMV[r][1];
    for (int i=0; i<32; i++){
      int c = q*32 + i;
      sC[r*272 + c] = f2bf((sF[r*264+c]-mu)*rs*g_attn[c] + beta_attn[c]);
    }
  }
  __syncthreads();

  // Phase C: ctx_p = tanh(ctx_ln @ W_ctx + b_ctx) -> regs (fp32) + sC (bf16)
  f32x4 cpv[2][4];
  {
    f32x4 acc[2][4] = {};
    for (int k0=0; k0<256; k0+=32){
      bf16x8 a[2], b[4];
      #pragma unroll
      for (int rt=0; rt<2; rt++)
        a[rt] = *reinterpret_cast<const bf16x8*>(sC + (rt*16+r16)*272 + k0 + kk);
      #pragma unroll
      for (int ct=0; ct<4; ct++)
        b[ct] = *reinterpret_cast<const bf16x8*>(wp + O_WCTXT + (cb+ct*16+r16)*256 + k0 + kk);
      #pragma unroll
      for (int rt=0; rt<2; rt++)
        #pragma unroll
        for (int ct=0; ct<4; ct++)
          acc[rt][ct] = mfma16(a[rt], b[ct], acc[rt][ct]);
    }
    #pragma unroll
    for (int rt=0; rt<2; rt++)
      #pragma unroll
      for (int ct=0; ct<4; ct++)
        #pragma unroll
        for (int v=0; v<4; v++)
          cpv[rt][ct][v] = tanh_(acc[rt][ct][v] + b_ctx[cb + ct*16 + r16]);
  }
  __syncthreads();  // all waves done reading sC (ctx_ln dead)
  #pragma unroll
  for (int rt=0; rt<2; rt++)
    #pragma unroll
    for (int ct=0; ct<4; ct++)
      #pragma unroll
      for (int v=0; v<4; v++){
        int lrow = rt*16 + vr4 + v, col = cb + ct*16 + r16;
        sC[lrow*272 + col] = f2bf(cpv[rt][ct][v]);
      }
  __syncthreads();

  // Phase D: alpha = sigmoid([gru_out|ctx_p] @ W_gate + b_gate); combine -> sF
  {
    f32x4 acc[2][4] = {};
    for (int k0=0; k0<512; k0+=32){
      bf16x8 a[2], b[4];
      if (k0 < 256){
        #pragma unroll
        for (int rt=0; rt<2; rt++)
          a[rt] = frag_f32(gruout_f + (size_t)(row0+rt*16+r16)*256 + k0 + kk);
      } else {
        #pragma unroll
        for (int rt=0; rt<2; rt++)
          a[rt] = *reinterpret_cast<const bf16x8*>(sC + (rt*16+r16)*272 + (k0-256) + kk);
      }
      #pragma unroll
      for (int ct=0; ct<4; ct++)
        b[ct] = *reinterpret_cast<const bf16x8*>(wp + O_WGT + (cb+ct*16+r16)*512 + k0 + kk);
      #pragma unroll
      for (int rt=0; rt<2; rt++)
        #pragma unroll
        for (int ct=0; ct<4; ct++)
          acc[rt][ct] = mfma16(a[rt], b[ct], acc[rt][ct]);
    }
    #pragma unroll
    for (int rt=0; rt<2; rt++)
      #pragma unroll
      for (int ct=0; ct<4; ct++)
        #pragma unroll
        for (int v=0; v<4; v++){
          int lrow = rt*16 + vr4 + v, grow = row0 + lrow, col = cb + ct*16 + r16;
          float al = sigm(acc[rt][ct][v] + b_gate[col]);
          float go = gruout_f[(size_t)grow*256 + col];
          sF[lrow*264 + col] = (1.f-al)*go + al*cpv[rt][ct][v];
        }
  }
  __syncthreads();

  // LN2 (g_out/beta_out): sF -> d_out h_corr
  ln_stats(sF, sPart, sMV, tid);
  {
    int r = tid>>3, q = tid&7;
    float mu = sMV[r][0], rs = sMV[r][1];
    int grow = row0 + r;
    for (int i=0; i<32; i++){
      int c = q*32 + i;
      d_out[(size_t)grow*256 + c] = (sF[r*264+c]-mu)*rs*g_out[c] + beta_out[c];
    }
  }
}

extern "C" void kernel_launch(void* const* d_in, const int* in_sizes, int n_in,
                              void* d_out, int out_size, void* d_ws, size_t ws_size,
                              hipStream_t stream)
{
  const float* inputs   = (const float*)d_in[0];
  const float* h_prev   = (const float*)d_in[1];
  const float* memory   = (const float*)d_in[2];
  const float* W_in     = (const float*)d_in[3];
  const float* b_in     = (const float*)d_in[4];
  const float* gru_k    = (const float*)d_in[5];
  const float* gru_rk   = (const float*)d_in[6];
  const float* gru_b    = (const float*)d_in[7];
  const float* Wq       = (const float*)d_in[8];
  const float* bq       = (const float*)d_in[9];
  const float* Wk       = (const float*)d_in[10];
  // d_in[11] = bk: cancels under softmax (constant over m) — not needed
  const float* Wv       = (const float*)d_in[12];
  const float* bv       = (const float*)d_in[13];
  const float* Wo       = (const float*)d_in[14];
  const float* bo       = (const float*)d_in[15];
  const float* g_attn   = (const float*)d_in[16];
  const float* beta_attn= (const float*)d_in[17];
  const float* g_out    = (const float*)d_in[18];
  const float* beta_out = (const float*)d_in[19];
  const float* W_ctx    = (const float*)d_in[20];
  const float* b_ctx    = (const float*)d_in[21];
  const float* W_gate   = (const float*)d_in[22];
  const float* b_gate   = (const float*)d_in[23];
  const float* W_mem    = (const float*)d_in[24];
  const float* b_mem    = (const float*)d_in[25];

  short* wp       = (short*)d_ws;
  float* gruout_f = (float*)((char*)d_ws + OB_GRUF);
  short* qkwm     = (short*)((char*)d_ws + OB_QK);
  float* out      = (float*)d_out;

  k_prep<<<W_TOTAL/256, 256, 0, stream>>>(W_in, gru_k, gru_rk, Wq, Wk, Wv, Wo,
                                          W_ctx, W_gate, W_mem, wp);
  k_gru <<<BN/32, 256, 0, stream>>>(inputs, h_prev, b_in, gru_b, bq, b_mem,
                                    wp, gruout_f, qkwm, out);
  k_attn<<<BN/4, 256, 0, stream>>>(memory, qkwm, out);
  k_out <<<BN/32, 256, 0, stream>>>(qkwm, wp, bv, bo, g_attn, beta_attn,
                                    b_ctx, b_gate, g_out, beta_out, gruout_f, out);
}